// Round 1
// baseline (867.699 us; speedup 1.0000x reference)
//
#include <hip/hip_runtime.h>
#include <math.h>

#define NB 1280000
#define D 128
#define DIN 2048
#define BB 256
#define MM 4096

constexpr float INV_TAU = 1.0f / 0.07f;
constexpr float GAMMA = 0.5f;

__device__ __forceinline__ float softplus_f(float x) {
    // log(1+exp(x)), stable
    return x > 20.0f ? x : log1pf(expf(x));
}

// ---------------- kernel 1: emb + pos + entries (one block per b) -------------
__global__ __launch_bounds__(256) void emb_kernel(
    const float* __restrict__ outputs, const float* __restrict__ W,
    const float* __restrict__ bias, const float* __restrict__ mb,
    const int* __restrict__ indices,
    float* __restrict__ emb, float* __restrict__ pos,
    float* __restrict__ entries)
{
    __shared__ float4 xs4[DIN / 4];   // 8 KB: outputs row
    __shared__ float zbuf[D];
    __shared__ float red[256];
    const int b = blockIdx.x;
    const int t = threadIdx.x;
    const int wave = t >> 6, lane = t & 63;

    const float4* out4 = (const float4*)(outputs + (size_t)b * DIN);
    xs4[t]       = out4[t];
    xs4[t + 256] = out4[t + 256];
    __syncthreads();

    const float4* W4 = (const float4*)W;
    for (int i = 0; i < 32; ++i) {
        int d = i * 4 + wave;
        const float4* wrow = W4 + (size_t)d * (DIN / 4);
        float acc = 0.0f;
        #pragma unroll
        for (int r = 0; r < 8; ++r) {
            float4 wv = wrow[r * 64 + lane];
            float4 xv = xs4[r * 64 + lane];
            acc += wv.x * xv.x + wv.y * xv.y + wv.z * xv.z + wv.w * xv.w;
        }
        #pragma unroll
        for (int s = 32; s > 0; s >>= 1) acc += __shfl_xor(acc, s);
        if (lane == 0) zbuf[d] = acc + bias[d];
    }
    __syncthreads();

    // l2 norm of z
    float z = (t < D) ? zbuf[t] : 0.0f;
    red[t] = z * z;
    __syncthreads();
    for (int s = 128; s > 0; s >>= 1) { if (t < s) red[t] += red[t + s]; __syncthreads(); }
    float inv = 1.0f / fmaxf(sqrtf(red[0]), 1e-12f);
    __syncthreads();
    float e = z * inv;
    if (t < D) emb[(size_t)b * D + t] = e;

    // pos = dot(emb, mb[indices[b]]) / tau
    int pidx = indices[b];
    float pm = (t < D) ? mb[(size_t)pidx * D + t] : 0.0f;
    red[t] = e * pm;
    __syncthreads();
    for (int s = 128; s > 0; s >>= 1) { if (t < s) red[t] += red[t + s]; __syncthreads(); }
    if (t == 0) pos[b] = red[0] * INV_TAU;
    __syncthreads();

    // entries = l2norm(gamma*pos_mem + (1-gamma)*emb)
    float en = GAMMA * pm + (1.0f - GAMMA) * e;
    red[t] = en * en;
    __syncthreads();
    for (int s = 128; s > 0; s >>= 1) { if (t < s) red[t] += red[t + s]; __syncthreads(); }
    float inv2 = 1.0f / fmaxf(sqrtf(red[0]), 1e-12f);
    if (t < D) entries[(size_t)b * D + t] = en * inv2;
}

// ---------------- kernel 2: neg gather + per-chunk online logsumexp ----------
// grid = BB*8 blocks; block (b, chunk c) handles m in [c*512, c*512+512)
__global__ __launch_bounds__(256) void neg_kernel(
    const float* __restrict__ mb, const int* __restrict__ ridx,
    const float* __restrict__ emb, float* __restrict__ neg,
    float* __restrict__ chunk_max, float* __restrict__ chunk_sum)
{
    __shared__ int idxs[512];
    __shared__ float gmax[8], gsum[8];
    const int blk = blockIdx.x;
    const int b = blk >> 3, c = blk & 7;
    const int m0 = c << 9;
    const int t = threadIdx.x;
    const int g = t >> 5, gl = t & 31;

    idxs[t]       = ridx[(size_t)b * MM + m0 + t];
    idxs[t + 256] = ridx[(size_t)b * MM + m0 + t + 256];
    const float4* emb4 = (const float4*)(emb + (size_t)b * D);
    float4 e4 = emb4[gl];
    __syncthreads();

    const float4* mb4 = (const float4*)mb;
    float* negrow = neg + (size_t)b * MM + m0;
    float mx = -INFINITY, sm = 0.0f;

    for (int it = 0; it < 32; ++it) {
        int r0 = it * 16 + g * 2;
        int i0 = idxs[r0], i1 = idxs[r0 + 1];
        float4 v0 = mb4[(size_t)i0 * 32 + gl];
        float4 v1 = mb4[(size_t)i1 * 32 + gl];
        float p0 = v0.x * e4.x + v0.y * e4.y + v0.z * e4.z + v0.w * e4.w;
        float p1 = v1.x * e4.x + v1.y * e4.y + v1.z * e4.z + v1.w * e4.w;
        #pragma unroll
        for (int s = 16; s > 0; s >>= 1) {
            p0 += __shfl_xor(p0, s);
            p1 += __shfl_xor(p1, s);
        }
        p0 *= INV_TAU; p1 *= INV_TAU;
        if (gl == 0) {
            negrow[r0] = p0; negrow[r0 + 1] = p1;
            float hi = fmaxf(p0, p1), lo = fminf(p0, p1);
            float pairsum = 1.0f + expf(lo - hi);
            if (hi > mx) { sm = sm * expf(mx - hi) + pairsum; mx = hi; }
            else         { sm += pairsum * expf(hi - mx); }
        }
    }
    if (gl == 0) { gmax[g] = mx; gsum[g] = sm; }
    __syncthreads();
    if (t == 0) {
        float Mx = gmax[0];
        for (int i = 1; i < 8; ++i) Mx = fmaxf(Mx, gmax[i]);
        float S = 0.0f;
        for (int i = 0; i < 8; ++i) S += gsum[i] * expf(gmax[i] - Mx);
        chunk_max[blk] = Mx;
        chunk_sum[blk] = S;
    }
}

// ---------------- kernel 3: combine chunks -> logC, data term ---------------
__global__ __launch_bounds__(256) void logc_kernel(
    const float* __restrict__ chunk_max, const float* __restrict__ chunk_sum,
    const float* __restrict__ pos, float* __restrict__ logC,
    float* __restrict__ data_sum, float* __restrict__ noise_sum)
{
    __shared__ float red[256];
    const int t = threadIdx.x;  // t == b
    float Mx = -INFINITY;
    for (int i = 0; i < 8; ++i) Mx = fmaxf(Mx, chunk_max[t * 8 + i]);
    float S = 0.0f;
    for (int i = 0; i < 8; ++i) S += chunk_sum[t * 8 + i] * expf(chunk_max[t * 8 + i] - Mx);
    float lc = Mx + logf(S);
    logC[t] = lc;
    red[t] = softplus_f(lc - pos[t]);  // -log_data_prob
    __syncthreads();
    for (int s = 128; s > 0; s >>= 1) { if (t < s) red[t] += red[t + s]; __syncthreads(); }
    if (t == 0) { data_sum[0] = red[0]; noise_sum[0] = 0.0f; }
}

// ---------------- kernel 4: noise loss over stored neg ----------------------
// grid = BB*MM/4/256 = 1024 blocks, float4 per thread
__global__ __launch_bounds__(256) void noise_kernel(
    const float* __restrict__ neg, const float* __restrict__ logC,
    float* __restrict__ noise_sum)
{
    __shared__ float red[256];
    const int t = threadIdx.x;
    size_t i = (size_t)blockIdx.x * 256 + t;      // float4 index
    int b = (int)(i >> 10);                       // MM/4 = 1024 float4 per row
    float lc = logC[b];
    float4 v = ((const float4*)neg)[i];
    float s = softplus_f(v.x - lc) + softplus_f(v.y - lc) +
              softplus_f(v.z - lc) + softplus_f(v.w - lc);
    red[t] = s;
    __syncthreads();
    for (int st = 128; st > 0; st >>= 1) { if (t < st) red[t] += red[t + st]; __syncthreads(); }
    if (t == 0) atomicAdd(noise_sum, red[0]);
}

// ---------------- kernel 5: finalize scalars --------------------------------
__global__ void final_kernel(const float* __restrict__ data_sum,
                             const float* __restrict__ noise_sum,
                             float* __restrict__ out)
{
    float dl = data_sum[0] / (float)BB;
    float nl = noise_sum[0] / (float)BB;
    out[0] = dl + nl;                 // loss
    out[1 + BB * D] = dl;             // data_loss
    out[2 + BB * D] = nl;             // noise_loss
}

extern "C" void kernel_launch(void* const* d_in, const int* in_sizes, int n_in,
                              void* d_out, int out_size, void* d_ws, size_t ws_size,
                              hipStream_t stream) {
    const float* outputs = (const float*)d_in[0];   // (B, DIN)
    const float* W       = (const float*)d_in[1];   // (D, DIN)
    const float* bias    = (const float*)d_in[2];   // (D,)
    const float* mb      = (const float*)d_in[3];   // (N, D)
    const int*   indices = (const int*)d_in[4];     // (B,)
    const int*   ridx    = (const int*)d_in[5];     // (B, M)

    float* out = (float*)d_out;
    float* ws  = (float*)d_ws;

    // workspace layout (floats)
    float* emb       = ws;                 // 32768
    float* pos       = emb + BB * D;       // 256
    float* chunk_max = pos + BB;           // 2048
    float* chunk_sum = chunk_max + BB * 8; // 2048
    float* logC      = chunk_sum + BB * 8; // 256
    float* data_sum  = logC + BB;          // 1
    float* noise_sum = data_sum + 1;       // 1
    float* neg       = ws + 37380;         // 1048576 (16B aligned)

    float* entries = out + 1;              // (B, D) at out[1..32768]

    emb_kernel<<<BB, 256, 0, stream>>>(outputs, W, bias, mb, indices, emb, pos, entries);
    neg_kernel<<<BB * 8, 256, 0, stream>>>(mb, ridx, emb, neg, chunk_max, chunk_sum);
    logc_kernel<<<1, 256, 0, stream>>>(chunk_max, chunk_sum, pos, logC, data_sum, noise_sum);
    noise_kernel<<<BB * MM / 4 / 256, 256, 0, stream>>>(neg, logC, noise_sum);
    final_kernel<<<1, 1, 0, stream>>>(data_sum, noise_sum, out);
}

// Round 2
// 860.355 us; speedup vs baseline: 1.0085x; 1.0085x over previous
//
#include <hip/hip_runtime.h>
#include <math.h>

#define NB 1280000
#define D 128
#define DIN 2048
#define BB 256
#define MM 4096

constexpr float INV_TAU = 1.0f / 0.07f;
constexpr float GAMMA = 0.5f;

__device__ __forceinline__ float softplus_f(float x) {
    // log(1+exp(x)), stable
    return x > 20.0f ? x : log1pf(expf(x));
}

// ---------------- kernel 1: emb + pos + entries (one block per b) -------------
__global__ __launch_bounds__(256) void emb_kernel(
    const float* __restrict__ outputs, const float* __restrict__ W,
    const float* __restrict__ bias, const float* __restrict__ mb,
    const int* __restrict__ indices,
    float* __restrict__ emb, float* __restrict__ pos,
    float* __restrict__ entries)
{
    __shared__ float4 xs4[DIN / 4];   // 8 KB: outputs row
    __shared__ float zbuf[D];
    __shared__ float red[256];
    const int b = blockIdx.x;
    const int t = threadIdx.x;
    const int wave = t >> 6, lane = t & 63;

    const float4* out4 = (const float4*)(outputs + (size_t)b * DIN);
    xs4[t]       = out4[t];
    xs4[t + 256] = out4[t + 256];
    __syncthreads();

    const float4* W4 = (const float4*)W;
    for (int i = 0; i < 32; ++i) {
        int d = i * 4 + wave;
        const float4* wrow = W4 + (size_t)d * (DIN / 4);
        float acc = 0.0f;
        #pragma unroll
        for (int r = 0; r < 8; ++r) {
            float4 wv = wrow[r * 64 + lane];
            float4 xv = xs4[r * 64 + lane];
            acc += wv.x * xv.x + wv.y * xv.y + wv.z * xv.z + wv.w * xv.w;
        }
        #pragma unroll
        for (int s = 32; s > 0; s >>= 1) acc += __shfl_xor(acc, s);
        if (lane == 0) zbuf[d] = acc + bias[d];
    }
    __syncthreads();

    // l2 norm of z
    float z = (t < D) ? zbuf[t] : 0.0f;
    red[t] = z * z;
    __syncthreads();
    for (int s = 128; s > 0; s >>= 1) { if (t < s) red[t] += red[t + s]; __syncthreads(); }
    float inv = 1.0f / fmaxf(sqrtf(red[0]), 1e-12f);
    __syncthreads();
    float e = z * inv;
    if (t < D) emb[(size_t)b * D + t] = e;

    // pos = dot(emb, mb[indices[b]]) / tau
    int pidx = indices[b];
    float pm = (t < D) ? mb[(size_t)pidx * D + t] : 0.0f;
    red[t] = e * pm;
    __syncthreads();
    for (int s = 128; s > 0; s >>= 1) { if (t < s) red[t] += red[t + s]; __syncthreads(); }
    if (t == 0) pos[b] = red[0] * INV_TAU;
    __syncthreads();

    // entries = l2norm(gamma*pos_mem + (1-gamma)*emb)
    float en = GAMMA * pm + (1.0f - GAMMA) * e;
    red[t] = en * en;
    __syncthreads();
    for (int s = 128; s > 0; s >>= 1) { if (t < s) red[t] += red[t + s]; __syncthreads(); }
    float inv2 = 1.0f / fmaxf(sqrtf(red[0]), 1e-12f);
    if (t < D) entries[(size_t)b * D + t] = en * inv2;
}

// ---------------- kernel 2: neg gather, MLP-rich two-phase -------------------
// grid = BB*8 blocks; block (b, chunk c) handles m in [c*512, c*512+512).
// Phase A: 8 groups of 32 lanes, each group computes 8 independent row-dots
//   per iteration (8 dwordx4 loads in flight, no loop-carried exp chain).
// Phase B: block-wide max + sum(exp) over the 512 LDS values.
__global__ __launch_bounds__(256) void neg_kernel(
    const float* __restrict__ mb, const int* __restrict__ ridx,
    const float* __restrict__ emb, float* __restrict__ neg,
    float* __restrict__ chunk_max, float* __restrict__ chunk_sum)
{
    __shared__ int idxs[512];
    __shared__ float pvals[512];
    __shared__ float wm[4], wsum[4];
    const int blk = blockIdx.x;
    const int b = blk >> 3, c = blk & 7;
    const int m0 = c << 9;
    const int t = threadIdx.x;
    const int g = t >> 5, gl = t & 31;      // 8 groups of 32 lanes
    const int wave = t >> 6, lane = t & 63;

    idxs[t]       = ridx[(size_t)b * MM + m0 + t];
    idxs[t + 256] = ridx[(size_t)b * MM + m0 + 256 + t];
    float4 e4 = ((const float4*)(emb + (size_t)b * D))[gl];
    __syncthreads();

    const float4* mb4 = (const float4*)mb;

    // Phase A: 8 iterations x 8 rows per group (8 groups x 64 rows = 512)
    for (int it = 0; it < 8; ++it) {
        const int r0 = it * 64 + g * 8;
        float4 v[8];
        #pragma unroll
        for (int j = 0; j < 8; ++j)
            v[j] = mb4[(size_t)idxs[r0 + j] * 32 + gl];
        float myp = 0.0f;
        #pragma unroll
        for (int j = 0; j < 8; ++j) {
            float p = v[j].x * e4.x + v[j].y * e4.y + v[j].z * e4.z + v[j].w * e4.w;
            #pragma unroll
            for (int s = 16; s > 0; s >>= 1) p += __shfl_xor(p, s);
            if (gl == j) myp = p;
        }
        if (gl < 8) pvals[r0 + gl] = myp * INV_TAU;
    }
    __syncthreads();

    // Phase B: coalesced global write + block softmax stats
    float v0 = pvals[t], v1 = pvals[t + 256];
    float* negrow = neg + (size_t)b * MM + m0;
    negrow[t]       = v0;
    negrow[t + 256] = v1;

    float m = fmaxf(v0, v1);
    #pragma unroll
    for (int s = 32; s > 0; s >>= 1) m = fmaxf(m, __shfl_xor(m, s));
    if (lane == 0) wm[wave] = m;
    __syncthreads();
    float Mx = fmaxf(fmaxf(wm[0], wm[1]), fmaxf(wm[2], wm[3]));
    float s2 = expf(v0 - Mx) + expf(v1 - Mx);
    #pragma unroll
    for (int s = 32; s > 0; s >>= 1) s2 += __shfl_xor(s2, s);
    if (lane == 0) wsum[wave] = s2;
    __syncthreads();
    if (t == 0) {
        chunk_max[blk] = Mx;
        chunk_sum[blk] = wsum[0] + wsum[1] + wsum[2] + wsum[3];
    }
}

// ---------------- kernel 3: combine chunks -> logC, data term ---------------
__global__ __launch_bounds__(256) void logc_kernel(
    const float* __restrict__ chunk_max, const float* __restrict__ chunk_sum,
    const float* __restrict__ pos, float* __restrict__ logC,
    float* __restrict__ data_sum, float* __restrict__ noise_sum)
{
    __shared__ float red[256];
    const int t = threadIdx.x;  // t == b
    float Mx = -INFINITY;
    for (int i = 0; i < 8; ++i) Mx = fmaxf(Mx, chunk_max[t * 8 + i]);
    float S = 0.0f;
    for (int i = 0; i < 8; ++i) S += chunk_sum[t * 8 + i] * expf(chunk_max[t * 8 + i] - Mx);
    float lc = Mx + logf(S);
    logC[t] = lc;
    red[t] = softplus_f(lc - pos[t]);  // -log_data_prob
    __syncthreads();
    for (int s = 128; s > 0; s >>= 1) { if (t < s) red[t] += red[t + s]; __syncthreads(); }
    if (t == 0) { data_sum[0] = red[0]; noise_sum[0] = 0.0f; }
}

// ---------------- kernel 4: noise loss over stored neg ----------------------
// grid = BB*MM/4/256 = 1024 blocks, float4 per thread
__global__ __launch_bounds__(256) void noise_kernel(
    const float* __restrict__ neg, const float* __restrict__ logC,
    float* __restrict__ noise_sum)
{
    __shared__ float red[256];
    const int t = threadIdx.x;
    size_t i = (size_t)blockIdx.x * 256 + t;      // float4 index
    int b = (int)(i >> 10);                       // MM/4 = 1024 float4 per row
    float lc = logC[b];
    float4 v = ((const float4*)neg)[i];
    float s = softplus_f(v.x - lc) + softplus_f(v.y - lc) +
              softplus_f(v.z - lc) + softplus_f(v.w - lc);
    red[t] = s;
    __syncthreads();
    for (int st = 128; st > 0; st >>= 1) { if (t < st) red[t] += red[t + st]; __syncthreads(); }
    if (t == 0) atomicAdd(noise_sum, red[0]);
}

// ---------------- kernel 5: finalize scalars --------------------------------
__global__ void final_kernel(const float* __restrict__ data_sum,
                             const float* __restrict__ noise_sum,
                             float* __restrict__ out)
{
    float dl = data_sum[0] / (float)BB;
    float nl = noise_sum[0] / (float)BB;
    out[0] = dl + nl;                 // loss
    out[1 + BB * D] = dl;             // data_loss
    out[2 + BB * D] = nl;             // noise_loss
}

extern "C" void kernel_launch(void* const* d_in, const int* in_sizes, int n_in,
                              void* d_out, int out_size, void* d_ws, size_t ws_size,
                              hipStream_t stream) {
    const float* outputs = (const float*)d_in[0];   // (B, DIN)
    const float* W       = (const float*)d_in[1];   // (D, DIN)
    const float* bias    = (const float*)d_in[2];   // (D,)
    const float* mb      = (const float*)d_in[3];   // (N, D)
    const int*   indices = (const int*)d_in[4];     // (B,)
    const int*   ridx    = (const int*)d_in[5];     // (B, M)

    float* out = (float*)d_out;
    float* ws  = (float*)d_ws;

    // workspace layout (floats)
    float* emb       = ws;                 // 32768
    float* pos       = emb + BB * D;       // 256
    float* chunk_max = pos + BB;           // 2048
    float* chunk_sum = chunk_max + BB * 8; // 2048
    float* logC      = chunk_sum + BB * 8; // 256
    float* data_sum  = logC + BB;          // 1
    float* noise_sum = data_sum + 1;       // 1
    float* neg       = ws + 37380;         // 1048576 floats (16B aligned)

    float* entries = out + 1;              // (B, D) at out[1..32768]

    emb_kernel<<<BB, 256, 0, stream>>>(outputs, W, bias, mb, indices, emb, pos, entries);
    neg_kernel<<<BB * 8, 256, 0, stream>>>(mb, ridx, emb, neg, chunk_max, chunk_sum);
    logc_kernel<<<1, 256, 0, stream>>>(chunk_max, chunk_sum, pos, logC, data_sum, noise_sum);
    noise_kernel<<<BB * MM / 4 / 256, 256, 0, stream>>>(neg, logC, noise_sum);
    final_kernel<<<1, 1, 0, stream>>>(data_sum, noise_sum, out);
}